// Round 5
// baseline (605.690 us; speedup 1.0000x reference)
//
#include <hip/hip_runtime.h>
#include <hip/hip_fp16.h>
#include <stdint.h>

typedef _Float16 f16;
typedef __attribute__((ext_vector_type(4))) _Float16 f16x4;
typedef __attribute__((ext_vector_type(8))) _Float16 f16x8;
typedef __attribute__((ext_vector_type(4))) float f32x4;

#define DEVI static __device__ __forceinline__

// ---- constants for this problem ----
#define C_DIM 512
#define M1    113288   // 8*289*49 window-token rows
#define M2    102152   // 8*12769 pixel rows
#define NWIN  289
#define NTOK  49
#define NHW   18496    // 8*289*8 head-windows

DEVI void load_lds16(const f16* g, f16* l) {
  __builtin_amdgcn_global_load_lds((const __attribute__((address_space(1))) void*)g,
                                   (__attribute__((address_space(3))) void*)l,
                                   16, 0, 0);
}

DEVI f32x4 mfma_16x16x32(f16x8 a, f16x8 b, f32x4 c) {
  return __builtin_amdgcn_mfma_f32_16x16x32_f16(a, b, c, 0, 0, 0);
}

// ---------------- x -> f16 (and zero page init) ----------------
__global__ void cvt_x_kernel(const float* __restrict__ x, f16* __restrict__ xh,
                             f16* __restrict__ zp) {
  if (blockIdx.x == 0 && threadIdx.x < 64) {
    ((int4*)zp)[threadIdx.x] = make_int4(0, 0, 0, 0);  // 1024 B zeros
  }
  const int n8 = 6537728;  // 52,301,824 / 8
  int i = blockIdx.x * blockDim.x + threadIdx.x;
  for (; i < n8; i += gridDim.x * blockDim.x) {
    const float4* p = (const float4*)(x) + (size_t)i * 2;
    const float4 a = p[0], b = p[1];
    f16x8 o;
    o[0] = (f16)a.x; o[1] = (f16)a.y; o[2] = (f16)a.z; o[3] = (f16)a.w;
    o[4] = (f16)b.x; o[5] = (f16)b.y; o[6] = (f16)b.z; o[7] = (f16)b.w;
    *(f16x8*)(xh + (size_t)i * 8) = o;
  }
}

// ---------------- W [K][N] -> Wt f16 [N][K] ----------------
__global__ void cvt_wT_kernel(const float* __restrict__ w, f16* __restrict__ wt,
                              int K, int N) {
  const int i = blockIdx.x * blockDim.x + threadIdx.x;
  if (i < K * N) {
    const int n = i / K;
    const int k = i - n * K;
    wt[i] = (f16)w[(size_t)k * N + n];
  }
}

// ---------------- GEMM: C[M][N] = gather(A)[M][512] @ Bt[N][512]^T ----------------
// Block tile 256x128 (4 waves, 128x64 per wave: 8 M-frags x 4 N-frags), BK=32,
// 2-phase double-buffered staging, 1-D grid tn-fastest + bijective XCD swizzle.
// MODE 0: A = xh (pixel rows), gather = window partition w/ zero pad;
//         q/k -> [hw][49][64] f16 (stride 3136), v -> [hw][49][64] f16 (stride 4096)
// MODE 1: A = ah (window-token rows), gather = window merge (crop); out -> fp32 + bias
template<int MODE>
__global__ __launch_bounds__(256, 2)
void gemm_kernel(const f16* __restrict__ A, const f16* __restrict__ Bt,
                 f16* __restrict__ qo, f16* __restrict__ ko, f16* __restrict__ vo,
                 float* __restrict__ out, const float* __restrict__ bias,
                 const f16* __restrict__ zp)
{
  __shared__ __align__(16) f16 As[2][8192];  // [256 rows][32 k], chunk-swizzled, dbuf
  __shared__ __align__(16) f16 Bs[2][4096];  // [128 rows][32 k]

  const int tid  = threadIdx.x;
  const int wave = tid >> 6;
  const int lane = tid & 63;
  const int l16  = lane & 15;
  const int lg   = lane >> 4;

  constexpr int NTN = (MODE == 0) ? 12 : 4;
  // bijective XCD swizzle: hardware bid -> logical wg, contiguous chunks per XCD
  const int nwg = gridDim.x;
  const int qq = nwg >> 3, rr = nwg & 7;
  const int xcd = blockIdx.x & 7, ib = blockIdx.x >> 3;
  const int wg = (xcd < rr ? xcd * (qq + 1) : rr * (qq + 1) + (xcd - rr) * qq) + ib;
  const int tn = wg % NTN;
  const int tm = wg / NTN;

  // ---- staging source pointers: 4 A-rows + 2 B-rows per thread ----
  const int srow  = tid >> 2;   // tile-local row base 0..63 (+64*c)
  const int chunk = tid & 3;    // physical 16B chunk within row
  const f16* ap[4];
  const f16* bp[2];
  #pragma unroll
  for (int c = 0; c < 4; ++c) {
    const int r  = srow + 64 * c;              // 0..255
    const int lc = chunk ^ ((r >> 1) & 3);     // logical k-chunk at this slot
    const int m  = tm * 256 + r;
    long src = 0; bool valid;
    if (MODE == 0) {
      const int b   = m / 14161;               // 289*49
      const int rem = m - b * 14161;
      const int wi  = rem / 49;
      const int t   = rem - wi * 49;
      const int wh = wi / 17, ww = wi - (wi / 17) * 17;
      const int th = t / 7,   tw = t - (t / 7) * 7;
      const int h = wh * 7 + th, w = ww * 7 + tw;
      valid = (m < M1) && (h < 113) && (w < 113);
      src = (long)b * 12769 + h * 113 + w;
    } else {
      const int b = m / 12769;
      const int p = m - b * 12769;
      const int h = p / 113, w = p - (p / 113) * 113;
      valid = (m < M2);
      src = (long)((b * NWIN + (h / 7) * 17 + (w / 7)) * NTOK + (h % 7) * 7 + (w % 7));
    }
    ap[c] = valid ? (A + src * C_DIM + lc * 8) : zp;
  }
  #pragma unroll
  for (int c = 0; c < 2; ++c) {
    const int r  = srow + 64 * c;              // 0..127
    const int lc = chunk ^ ((r >> 1) & 3);
    bp[c] = Bt + (long)(tn * 128 + r) * C_DIM + lc * 8;
  }

  // ---- LDS fragment read byte-offsets (constant across K loop) ----
  int aoff[8], boff[4];
  #pragma unroll
  for (int i = 0; i < 8; ++i) {
    const int ra = (wave >> 1) * 128 + i * 16 + l16;
    aoff[i] = ra * 64 + ((lg ^ ((ra >> 1) & 3)) * 16);
  }
  #pragma unroll
  for (int j = 0; j < 4; ++j) {
    const int rb = (wave & 1) * 64 + j * 16 + l16;
    boff[j] = rb * 64 + ((lg ^ ((rb >> 1) & 3)) * 16);
  }

  f32x4 acc[8][4];
  #pragma unroll
  for (int i = 0; i < 8; ++i)
    #pragma unroll
    for (int j = 0; j < 4; ++j)
      acc[i][j] = (f32x4){0.f, 0.f, 0.f, 0.f};

  // wave-uniform LDS staging dests: wave w covers rows 16w+64c, lane adds l*16B
  // ---- prologue: stage tile 0 into buffer 0 ----
  #pragma unroll
  for (int c = 0; c < 4; ++c) {
    load_lds16(ap[c], &As[0][(16 * wave + 64 * c) * 32]);
    ap[c] += 32;
  }
  #pragma unroll
  for (int c = 0; c < 2; ++c) {
    load_lds16(bp[c], &Bs[0][(16 * wave + 64 * c) * 32]);
    bp[c] += 32;
  }
  __syncthreads();                       // drains vmcnt(0)

  int cur = 0;
  for (int kk = 0; kk < 15; ++kk) {      // K = 512 = 16 * 32; last tile peeled
    // issue next-tile loads into the other buffer (fly during compute)
    #pragma unroll
    for (int c = 0; c < 4; ++c) {
      load_lds16(ap[c], &As[cur ^ 1][(16 * wave + 64 * c) * 32]);
      ap[c] += 32;
    }
    #pragma unroll
    for (int c = 0; c < 2; ++c) {
      load_lds16(bp[c], &Bs[cur ^ 1][(16 * wave + 64 * c) * 32]);
      bp[c] += 32;
    }

    f16x8 af[8], bf[4];
    #pragma unroll
    for (int i = 0; i < 8; ++i) af[i] = *(const f16x8*)((const char*)&As[cur][0] + aoff[i]);
    #pragma unroll
    for (int j = 0; j < 4; ++j) bf[j] = *(const f16x8*)((const char*)&Bs[cur][0] + boff[j]);
    #pragma unroll
    for (int i = 0; i < 8; ++i)
      #pragma unroll
      for (int j = 0; j < 4; ++j)
        acc[i][j] = mfma_16x16x32(af[i], bf[j], acc[i][j]);

    __syncthreads();                     // vmcnt(0)+lgkmcnt(0) drain then barrier
    cur ^= 1;
  }
  {                                      // final tile: compute only
    f16x8 af[8], bf[4];
    #pragma unroll
    for (int i = 0; i < 8; ++i) af[i] = *(const f16x8*)((const char*)&As[cur][0] + aoff[i]);
    #pragma unroll
    for (int j = 0; j < 4; ++j) bf[j] = *(const f16x8*)((const char*)&Bs[cur][0] + boff[j]);
    #pragma unroll
    for (int i = 0; i < 8; ++i)
      #pragma unroll
      for (int j = 0; j < 4; ++j)
        acc[i][j] = mfma_16x16x32(af[i], bf[j], acc[i][j]);
  }

  // ---- epilogue ----
  const int rowb = tm * 256 + (wave >> 1) * 128 + lg * 4;
  const int colb = tn * 128 + (wave & 1) * 64 + l16;
  if (MODE == 0) {
    f16* outw = (tn < 4) ? qo : (tn < 8) ? ko : vo;
    const size_t stride = (tn < 8) ? 3136 : 4096;
    #pragma unroll
    for (int i = 0; i < 8; ++i) {
      #pragma unroll
      for (int j = 0; j < 4; ++j) {
        const int col  = colb + j * 16;
        const int head = (col >> 6) & 7;
        const int d    = col & 63;
        #pragma unroll
        for (int rg = 0; rg < 4; ++rg) {
          const int m = rowb + i * 16 + rg;
          if (m < M1) {
            const int bwi = m / 49;
            const int t   = m - bwi * 49;
            const size_t hw = (size_t)(bwi * 8 + head);
            outw[hw * stride + t * 64 + d] = (f16)acc[i][j][rg];
          }
        }
      }
    }
  } else {
    #pragma unroll
    for (int i = 0; i < 8; ++i) {
      #pragma unroll
      for (int j = 0; j < 4; ++j) {
        const int col = colb + j * 16;
        const float bb = bias[col];
        #pragma unroll
        for (int rg = 0; rg < 4; ++rg) {
          const int m = rowb + i * 16 + rg;
          if (m < M2) out[(size_t)m * C_DIM + col] = acc[i][j][rg] + bb;
        }
      }
    }
  }
}

// ---------------- MFMA attention: one wave per (b, window, head) ----------------
// S^T = K*Q^T (64x64, keys 49..63 -> P forced 0); exp w/o max-sub (|S*scale| <~ 2);
// P normalized fp32 -> f16 -> swizzled LDS; V tile loaded early [t][d], transposed
// in-register -> swizzled LDS [d][t] half-tiles; O = P*V. Padded q-rows never stored.
__global__ __launch_bounds__(256)
void attn_kernel(const f16* __restrict__ qg, const f16* __restrict__ kg,
                 const f16* __restrict__ vg, f16* __restrict__ og)
{
  __shared__ __align__(16) f16 plds[4][4096];  // per-wave [64q][64key], XOR-swizzled
  __shared__ __align__(16) f16 vlds[4][2048];  // per-wave [32d][64t] half, XOR-swizzled
  const int tid  = threadIdx.x;
  const int wv   = tid >> 6;
  const int lane = tid & 63;
  const int g    = lane >> 4;
  const int c    = lane & 15;
  const int hw   = blockIdx.x * 4 + wv;
  const int bwi  = hw >> 3;
  const int head = hw & 7;
  const int wi   = bwi % NWIN;
  const size_t bqk = (size_t)hw * 3136;
  const f16* vp = vg + (size_t)hw * 4096;

  // ---- V tile -> registers early (latency hides under QK^T); zero pad rows ----
  f16x8 vreg[8];
  #pragma unroll
  for (int d0 = 0; d0 < 8; ++d0)
    vreg[d0] = *(const f16x8*)(vp + lane * 64 + d0 * 8);
  if (lane >= 49) {
    #pragma unroll
    for (int d0 = 0; d0 < 8; ++d0) vreg[d0] = (f16x8){};
  }

  // pad-bit mask for tokens 0..48 of this window
  const int wh = wi / 17, ww = wi - (wi / 17) * 17;
  unsigned long long pm = 0;
  if (wh == 16) pm |= (((1ull << 49) - 1) & ~0x7Full);           // rows th>=1
  if (ww == 16) {
    unsigned long long cm = 0;
    #pragma unroll
    for (int r7 = 0; r7 < 7; ++r7) cm |= 0x7Eull << (7 * r7);    // cols tw>=1
    pm |= cm;
  }

  // ---- S^T = K * Q^T ----
  f32x4 acc[4][4];
  #pragma unroll
  for (int i = 0; i < 4; ++i)
    #pragma unroll
    for (int j = 0; j < 4; ++j) acc[i][j] = (f32x4){0.f, 0.f, 0.f, 0.f};

  const f16* kp = kg + bqk;
  const f16* qp = qg + bqk;
  #pragma unroll
  for (int s = 0; s < 2; ++s) {
    f16x8 kf[4], qf[4];
    #pragma unroll
    for (int i = 0; i < 4; ++i) kf[i] = *(const f16x8*)(kp + (16 * i + c) * 64 + 32 * s + 8 * g);
    #pragma unroll
    for (int j = 0; j < 4; ++j) qf[j] = *(const f16x8*)(qp + (16 * j + c) * 64 + 32 * s + 8 * g);
    #pragma unroll
    for (int i = 0; i < 4; ++i)
      #pragma unroll
      for (int j = 0; j < 4; ++j)
        acc[i][j] = mfma_16x16x32(kf[i], qf[j], acc[i][j]);
  }

  // ---- mask + exp + per-query denom (q = 16j + c; key = 16i + 4g + r) ----
  float invs[4];
  #pragma unroll
  for (int j = 0; j < 4; ++j) {
    const int q = 16 * j + c;
    const int padq = (int)((pm >> q) & 1);
    float sj = 0.f;
    #pragma unroll
    for (int i = 0; i < 4; ++i) {
      #pragma unroll
      for (int r = 0; r < 4; ++r) {
        const int key = 16 * i + 4 * g + r;
        const int padk = (int)((pm >> key) & 1);
        float sv = acc[i][j][r] * 0.125f + ((padk ^ padq) ? -1000.f : 0.f);
        float p = __expf(sv);
        if (i == 3) p = ((4 * g + r) == 0) ? p : 0.f;   // keys >= 49 forced 0
        acc[i][j][r] = p;
        sj += p;
      }
    }
    invs[j] = sj;
  }
  #pragma unroll
  for (int j = 0; j < 4; ++j) {
    float sj = invs[j];
    sj += __shfl_xor(sj, 16);
    sj += __shfl_xor(sj, 32);
    invs[j] = 1.0f / sj;
  }

  // ---- pack normalized P to f16, write LDS [q][key] (byte ^= (q&7)<<4) ----
  f16* pl = &plds[wv][0];
  const int swz = (c & 7) << 4;   // c&7 == q&7 for all j
  #pragma unroll
  for (int j = 0; j < 4; ++j) {
    const int q = 16 * j + c;
    const float inv = invs[j];
    #pragma unroll
    for (int i = 0; i < 4; ++i) {
      f16x4 pk;
      pk[0] = (f16)(acc[i][j][0] * inv);
      pk[1] = (f16)(acc[i][j][1] * inv);
      pk[2] = (f16)(acc[i][j][2] * inv);
      pk[3] = (f16)(acc[i][j][3] * inv);
      *(f16x4*)((char*)pl + q * 128 + ((32 * i + 8 * g) ^ swz)) = pk;
    }
  }

  // ---- O = P * V in two d-halves; V^T built in LDS from vreg ----
  f16* vl = &vlds[wv][0];
  f32x4 o[4][4];
  #pragma unroll
  for (int i = 0; i < 4; ++i)
    #pragma unroll
    for (int j = 0; j < 4; ++j) o[i][j] = (f32x4){0.f, 0.f, 0.f, 0.f};

  #pragma unroll
  for (int h = 0; h < 2; ++h) {
    // transpose-write d rows [32h, 32h+32): element j of vreg[d0] -> row (8*d0+j)&31, col t=lane
    #pragma unroll
    for (int q4 = 0; q4 < 4; ++q4) {
      const int d0 = 4 * h + q4;
      #pragma unroll
      for (int j = 0; j < 8; ++j) {
        const int dr = (8 * d0 + j) & 31;
        *(f16*)((char*)vl + dr * 128 + ((lane * 2) ^ (j << 4))) = vreg[d0][j];
      }
    }
    // WAR safety: half-0 frag data is consumed (lgkmcnt) before half-1 writes issue;
    // DS ops per-wave are processed in order.
    #pragma unroll
    for (int s = 0; s < 2; ++s) {
      f16x8 vf[2], pf[4];
      #pragma unroll
      for (int n = 0; n < 2; ++n)
        vf[n] = *(const f16x8*)((const char*)vl + (16 * n + c) * 128 + ((64 * s + 16 * g) ^ swz));
      #pragma unroll
      for (int jq = 0; jq < 4; ++jq)
        pf[jq] = *(const f16x8*)((const char*)pl + (16 * jq + c) * 128 + ((64 * s + 16 * g) ^ swz));
      #pragma unroll
      for (int jq = 0; jq < 4; ++jq)
        #pragma unroll
        for (int n = 0; n < 2; ++n)
          o[jq][2 * h + n] = mfma_16x16x32(pf[jq], vf[n], o[jq][2 * h + n]);
    }
  }

  // ---- store O rows q = 16jq + 4g + r (q<49), cols d = 16n + c ----
  f16* ob = og + ((size_t)bwi * 49) * 512 + head * 64;
  #pragma unroll
  for (int jq = 0; jq < 4; ++jq) {
    #pragma unroll
    for (int r = 0; r < 4; ++r) {
      const int q = 16 * jq + 4 * g + r;
      if (q < 49) {
        #pragma unroll
        for (int n = 0; n < 4; ++n)
          ob[(size_t)q * 512 + 16 * n + c] = (f16)o[jq][n][r];
      }
    }
  }
}

extern "C" void kernel_launch(void* const* d_in, const int* in_sizes, int n_in,
                              void* d_out, int out_size, void* d_ws, size_t ws_size,
                              hipStream_t stream)
{
  const float* x     = (const float*)d_in[0];
  const float* wqkv  = (const float*)d_in[1];
  const float* wproj = (const float*)d_in[2];
  const float* bproj = (const float*)d_in[3];
  float* out = (float*)d_out;

  // workspace layout (bytes); xh and ah share a region (xh dead before attn)
  char* ws = (char*)d_ws;
  f16* zp = (f16*)ws;                               // 1,024 B
  f16* xh = (f16*)(ws + 1024);                      // 104,603,648 B (region 116,006,912)
  f16* ah = xh;                                     // 116,006,912 B (after gemm1)
  f16* qh = (f16*)(ws + 1024 + 116006912LL);        // 116,006,912 B
  f16* kh = qh + 58003456LL;                        // 116,006,912 B
  f16* vh = kh + 58003456LL;                        // 151,519,232 B ([hw][64-stride][64])
  f16* wqkvT  = vh + 75759616LL;                    //   1,572,864 B
  f16* wprojT = wqkvT + 786432LL;                   //     524,288 B  (~501.6 MB total)

  cvt_x_kernel<<<2048, 256, 0, stream>>>(x, xh, zp);
  cvt_wT_kernel<<<(1536 * 512 + 255) / 256, 256, 0, stream>>>(wqkv, wqkvT, 512, 1536);
  cvt_wT_kernel<<<(512 * 512 + 255) / 256, 256, 0, stream>>>(wproj, wprojT, 512, 512);

  // 443 M-tiles of 256 x 12 N-tiles of 128
  gemm_kernel<0><<<443 * 12, 256, 0, stream>>>(xh, wqkvT, qh, kh, vh, nullptr, nullptr, zp);

  attn_kernel<<<NHW / 4, 256, 0, stream>>>(qh, kh, vh, ah);

  // 400 M-tiles of 256 x 4 N-tiles of 128
  gemm_kernel<1><<<400 * 4, 256, 0, stream>>>(ah, wprojT, nullptr, nullptr, nullptr, out, bproj, zp);
}

// Round 6
// 567.879 us; speedup vs baseline: 1.0666x; 1.0666x over previous
//
#include <hip/hip_runtime.h>
#include <hip/hip_fp16.h>
#include <stdint.h>

typedef _Float16 f16;
typedef __attribute__((ext_vector_type(4))) _Float16 f16x4;
typedef __attribute__((ext_vector_type(8))) _Float16 f16x8;
typedef __attribute__((ext_vector_type(4))) float f32x4;

#define DEVI static __device__ __forceinline__

// ---- constants for this problem ----
#define C_DIM 512
#define M1    113288   // 8*289*49 window-token rows
#define M2    102152   // 8*12769 pixel rows
#define NWIN  289
#define NTOK  49
#define NHW   18496    // 8*289*8 head-windows

DEVI void load_lds16(const f16* g, f16* l) {
  __builtin_amdgcn_global_load_lds((const __attribute__((address_space(1))) void*)g,
                                   (__attribute__((address_space(3))) void*)l,
                                   16, 0, 0);
}

DEVI f32x4 mfma_16x16x32(f16x8 a, f16x8 b, f32x4 c) {
  return __builtin_amdgcn_mfma_f32_16x16x32_f16(a, b, c, 0, 0, 0);
}

// ---------------- x -> f16 (and zero page init) ----------------
__global__ void cvt_x_kernel(const float* __restrict__ x, f16* __restrict__ xh,
                             f16* __restrict__ zp) {
  if (blockIdx.x == 0 && threadIdx.x < 64) {
    ((int4*)zp)[threadIdx.x] = make_int4(0, 0, 0, 0);  // 1024 B zeros
  }
  const int n8 = 6537728;  // 52,301,824 / 8
  int i = blockIdx.x * blockDim.x + threadIdx.x;
  for (; i < n8; i += gridDim.x * blockDim.x) {
    const float4* p = (const float4*)(x) + (size_t)i * 2;
    const float4 a = p[0], b = p[1];
    f16x8 o;
    o[0] = (f16)a.x; o[1] = (f16)a.y; o[2] = (f16)a.z; o[3] = (f16)a.w;
    o[4] = (f16)b.x; o[5] = (f16)b.y; o[6] = (f16)b.z; o[7] = (f16)b.w;
    *(f16x8*)(xh + (size_t)i * 8) = o;
  }
}

// ---------------- W [K][N] -> Wt f16 [N][K] ----------------
__global__ void cvt_wT_kernel(const float* __restrict__ w, f16* __restrict__ wt,
                              int K, int N) {
  const int i = blockIdx.x * blockDim.x + threadIdx.x;
  if (i < K * N) {
    const int n = i / K;
    const int k = i - n * K;
    wt[i] = (f16)w[(size_t)k * N + n];
  }
}

// ================= 8-phase GEMM: C[M][N] = gather(A)[M][512] @ Bt[N][512]^T =====
// BM=BN=256, BK=64, 512 threads (8 waves, 2M x 4N), per-wave C = 128x64.
// LDS: per operand 8 quarter-slots (64 rows x 64 k, 8KB each) = 128 KB total.
//   slot = 4*(ktile&1) + quarter. Chunk-XOR swizzle: phys chunk = logical ^ (row&7),
//   realized via inverse-swizzled GLOBAL source + linear gload_lds dest (rule #21).
// Schedule per K-tile t (4 phases, computing from parity P=t&1, staging tile t+1):
//   p0 (mh0,kh0): stage A q0,q2   p1 (mh0,kh1): stage B q0..q3  [vmcnt(6)]
//   p2 (mh1,kh0): no stage        p3 (mh1,kh1): stage A q1,q3   [vmcnt(2)]
// Each phase: 8 ds_read_b128 + stage + barrier + lgkmcnt(0) + 16 MFMA + barrier.
// MODE 0: A = xh (pixel rows, window-partition gather w/ zero pad);
//         q/k -> [hw][49][64] (stride 3136), v -> [hw][49][64] (stride 4096)
// MODE 1: A = ah (window-token rows, window-merge gather); out -> fp32 + bias
template<int MODE>
__global__ __launch_bounds__(512, 2)
void gemm_kernel(const f16* __restrict__ A, const f16* __restrict__ Bt,
                 f16* __restrict__ qo, f16* __restrict__ ko, f16* __restrict__ vo,
                 float* __restrict__ out, const float* __restrict__ bias,
                 const f16* __restrict__ zp)
{
  __shared__ __align__(16) f16 Aq[8][4096];  // 64 KB
  __shared__ __align__(16) f16 Bq[8][4096];  // 64 KB

  const int tid  = threadIdx.x;
  const int wave = tid >> 6;
  const int lane = tid & 63;
  const int l16  = lane & 15;
  const int g    = lane >> 4;
  const int wm   = wave >> 2;     // 0..1
  const int wn   = wave & 3;      // 0..3

  constexpr int NTN = (MODE == 0) ? 6 : 2;
  // bijective XCD swizzle, tn-fastest
  const int nwg = gridDim.x;
  const int qq = nwg >> 3, rr = nwg & 7;
  const int xcd = blockIdx.x & 7, ib = blockIdx.x >> 3;
  const int wg = (xcd < rr ? xcd * (qq + 1) : rr * (qq + 1) + (xcd - rr) * qq) + ib;
  const int tn = wg % NTN;
  const int tm = wg / NTN;

  // ---- staging source pointers (one 16B chunk per thread per call) ----
  const int srow  = tid >> 3;   // 0..63 row within quarter
  const int chunk = tid & 7;    // phys chunk (= linear LDS slot)
  const int lc    = chunk ^ (srow & 7);  // logical k-chunk fetched into this slot
  const f16* asrc[4];
  const f16* bsrc[4];
  #pragma unroll
  for (int q = 0; q < 4; ++q) {
    const int m = tm * 256 + q * 64 + srow;
    long src = 0; bool valid;
    if (MODE == 0) {
      const int b   = m / 14161;               // 289*49
      const int rem = m - b * 14161;
      const int wi  = rem / 49;
      const int t   = rem - wi * 49;
      const int wh = wi / 17, ww = wi - (wi / 17) * 17;
      const int th = t / 7,   tw = t - (t / 7) * 7;
      const int h = wh * 7 + th, w = ww * 7 + tw;
      valid = (m < M1) && (h < 113) && (w < 113);
      src = (long)b * 12769 + h * 113 + w;
    } else {
      const int b = m / 12769;
      const int p = m - b * 12769;
      const int h = p / 113, w = p - (p / 113) * 113;
      valid = (m < M2);
      src = (long)((b * NWIN + (h / 7) * 17 + (w / 7)) * NTOK + (h % 7) * 7 + (w % 7));
    }
    asrc[q] = valid ? (A + src * C_DIM + lc * 8) : zp;
    bsrc[q] = Bt + (long)(tn * 256 + q * 64 + srow) * C_DIM + lc * 8;
  }

  // ---- ds_read byte offsets within a slot (kh=0; kh=1 => ^64) ----
  int aoff[4], boff[4];
  #pragma unroll
  for (int i = 0; i < 4; ++i) {
    const int ra = 16 * i + l16;
    aoff[i] = ra * 128 + ((g ^ (l16 & 7)) * 16);
    boff[i] = aoff[i];             // same formula for B quarters
  }

  f32x4 acc[8][4];
  #pragma unroll
  for (int i = 0; i < 8; ++i)
    #pragma unroll
    for (int j = 0; j < 4; ++j)
      acc[i][j] = (f32x4){0.f, 0.f, 0.f, 0.f};

  const int wofs = wave * 512;     // per-wave LDS staging base (f16 units)
  const char* AqBase = (const char*)&Aq[0][0];
  const char* BqBase = (const char*)&Bq[0][0];

  // ---- prologue: stage K-tile 0 into parity 0 ----
  load_lds16(asrc[0], &Aq[0][wofs]);
  load_lds16(asrc[2], &Aq[2][wofs]);
  load_lds16(bsrc[0], &Bq[0][wofs]);
  load_lds16(bsrc[1], &Bq[1][wofs]);
  load_lds16(bsrc[2], &Bq[2][wofs]);
  load_lds16(bsrc[3], &Bq[3][wofs]);
  load_lds16(asrc[1], &Aq[1][wofs]);
  load_lds16(asrc[3], &Aq[3][wofs]);
  #pragma unroll
  for (int q = 0; q < 4; ++q) { asrc[q] += 64; bsrc[q] += 64; }
  asm volatile("s_waitcnt vmcnt(2)" ::: "memory");   // A q1,q3 may still fly
  __builtin_amdgcn_s_barrier();

#define PHASE(MH, KH, STAGE_CODE, TAIL_CODE)                                    \
  do {                                                                          \
    const char* Ab = AqBase + (size_t)((PA + 2 * wm + (MH)) * 8192);            \
    const char* Bb = BqBase + (size_t)((PA + wn) * 8192);                       \
    f16x8 af[4], bf[4];                                                         \
    _Pragma("unroll")                                                           \
    for (int i = 0; i < 4; ++i) af[i] = *(const f16x8*)(Ab + (aoff[i] ^ ((KH) * 64))); \
    _Pragma("unroll")                                                           \
    for (int j = 0; j < 4; ++j) bf[j] = *(const f16x8*)(Bb + (boff[j] ^ ((KH) * 64))); \
    STAGE_CODE;                                                                 \
    __builtin_amdgcn_s_barrier();                                               \
    asm volatile("s_waitcnt lgkmcnt(0)" ::: "memory");                          \
    __builtin_amdgcn_sched_barrier(0);                                          \
    __builtin_amdgcn_s_setprio(1);                                              \
    _Pragma("unroll")                                                           \
    for (int i = 0; i < 4; ++i)                                                 \
      _Pragma("unroll")                                                         \
      for (int j = 0; j < 4; ++j)                                               \
        acc[(MH) * 4 + i][j] = mfma_16x16x32(af[i], bf[j], acc[(MH) * 4 + i][j]); \
    __builtin_amdgcn_s_setprio(0);                                              \
    TAIL_CODE;                                                                  \
    __builtin_amdgcn_s_barrier();                                               \
  } while (0)

  // ---- main loop: iters 0..6 compute tile t, stage tile t+1 ----
  for (int t = 0; t < 7; ++t) {
    const int PA  = (t & 1) * 4;       // compute parity slots
    const int PB1 = 4 - PA;            // staging parity slots (t+1)
    PHASE(0, 0,
      { load_lds16(asrc[0], &Aq[PB1 + 0][wofs]);
        load_lds16(asrc[2], &Aq[PB1 + 2][wofs]); },
      {});
    PHASE(0, 1,
      { load_lds16(bsrc[0], &Bq[PB1 + 0][wofs]);
        load_lds16(bsrc[1], &Bq[PB1 + 1][wofs]);
        load_lds16(bsrc[2], &Bq[PB1 + 2][wofs]);
        load_lds16(bsrc[3], &Bq[PB1 + 3][wofs]); },
      { asm volatile("s_waitcnt vmcnt(6)" ::: "memory"); });
    PHASE(1, 0, {}, {});
    PHASE(1, 1,
      { load_lds16(asrc[1], &Aq[PB1 + 1][wofs]);
        load_lds16(asrc[3], &Aq[PB1 + 3][wofs]);
        _Pragma("unroll")
        for (int q = 0; q < 4; ++q) { asrc[q] += 64; bsrc[q] += 64; } },
      { asm volatile("s_waitcnt vmcnt(2)" ::: "memory"); });
  }
  // ---- peeled last K-tile (t=7, parity 1): no staging ----
  {
    const int PA = 4;
    PHASE(0, 0, {}, {});
    PHASE(0, 1, {}, { asm volatile("s_waitcnt vmcnt(0)" ::: "memory"); });
    PHASE(1, 0, {}, {});
    PHASE(1, 1, {}, {});
  }
#undef PHASE

  // ---- epilogue ----
  const int rowb = tm * 256 + wm * 128 + g * 4;
  const int colb = tn * 256 + wn * 64 + l16;
  if (MODE == 0) {
    const int cwi  = tn * 4 + wn;                   // 64-col strip index 0..23
    f16* outw = (cwi < 8) ? qo : (cwi < 16) ? ko : vo;
    const size_t stride = (cwi < 16) ? 3136 : 4096;
    const int head = cwi & 7;
    #pragma unroll
    for (int mh = 0; mh < 2; ++mh) {
      #pragma unroll
      for (int i = 0; i < 4; ++i) {
        #pragma unroll
        for (int rg = 0; rg < 4; ++rg) {
          const int m = rowb + mh * 64 + i * 16 + rg;
          if (m < M1) {
            const int bwi = m / 49;
            const int t   = m - bwi * 49;
            f16* orow = outw + (size_t)(bwi * 8 + head) * stride + t * 64 + l16;
            #pragma unroll
            for (int j = 0; j < 4; ++j)
              orow[j * 16] = (f16)acc[mh * 4 + i][j][rg];
          }
        }
      }
    }
  } else {
    float bb[4];
    #pragma unroll
    for (int j = 0; j < 4; ++j) bb[j] = bias[colb + j * 16];
    #pragma unroll
    for (int mh = 0; mh < 2; ++mh) {
      #pragma unroll
      for (int i = 0; i < 4; ++i) {
        #pragma unroll
        for (int rg = 0; rg < 4; ++rg) {
          const int m = rowb + mh * 64 + i * 16 + rg;
          if (m < M2) {
            float* orow = out + (size_t)m * C_DIM + colb;
            #pragma unroll
            for (int j = 0; j < 4; ++j)
              orow[j * 16] = acc[mh * 4 + i][j][rg] + bb[j];
          }
        }
      }
    }
  }
}

// ---------------- MFMA attention: one wave per (b, window, head) ----------------
__global__ __launch_bounds__(256)
void attn_kernel(const f16* __restrict__ qg, const f16* __restrict__ kg,
                 const f16* __restrict__ vg, f16* __restrict__ og)
{
  __shared__ __align__(16) f16 plds[4][4096];  // per-wave [64q][64key], XOR-swizzled
  __shared__ __align__(16) f16 vlds[4][2048];  // per-wave [32d][64t] half, XOR-swizzled
  const int tid  = threadIdx.x;
  const int wv   = tid >> 6;
  const int lane = tid & 63;
  const int g    = lane >> 4;
  const int c    = lane & 15;
  const int hw   = blockIdx.x * 4 + wv;
  const int bwi  = hw >> 3;
  const int head = hw & 7;
  const int wi   = bwi % NWIN;
  const size_t bqk = (size_t)hw * 3136;
  const f16* vp = vg + (size_t)hw * 4096;

  // ---- V tile -> registers early (latency hides under QK^T); zero pad rows ----
  f16x8 vreg[8];
  #pragma unroll
  for (int d0 = 0; d0 < 8; ++d0)
    vreg[d0] = *(const f16x8*)(vp + lane * 64 + d0 * 8);
  if (lane >= 49) {
    #pragma unroll
    for (int d0 = 0; d0 < 8; ++d0) vreg[d0] = (f16x8){};
  }

  // pad-bit mask for tokens 0..48 of this window
  const int wh = wi / 17, ww = wi - (wi / 17) * 17;
  unsigned long long pm = 0;
  if (wh == 16) pm |= (((1ull << 49) - 1) & ~0x7Full);           // rows th>=1
  if (ww == 16) {
    unsigned long long cm = 0;
    #pragma unroll
    for (int r7 = 0; r7 < 7; ++r7) cm |= 0x7Eull << (7 * r7);    // cols tw>=1
    pm |= cm;
  }

  // ---- S^T = K * Q^T ----
  f32x4 acc[4][4];
  #pragma unroll
  for (int i = 0; i < 4; ++i)
    #pragma unroll
    for (int j = 0; j < 4; ++j) acc[i][j] = (f32x4){0.f, 0.f, 0.f, 0.f};

  const f16* kp = kg + bqk;
  const f16* qp = qg + bqk;
  #pragma unroll
  for (int s = 0; s < 2; ++s) {
    f16x8 kf[4], qf[4];
    #pragma unroll
    for (int i = 0; i < 4; ++i) kf[i] = *(const f16x8*)(kp + (16 * i + c) * 64 + 32 * s + 8 * g);
    #pragma unroll
    for (int j = 0; j < 4; ++j) qf[j] = *(const f16x8*)(qp + (16 * j + c) * 64 + 32 * s + 8 * g);
    #pragma unroll
    for (int i = 0; i < 4; ++i)
      #pragma unroll
      for (int j = 0; j < 4; ++j)
        acc[i][j] = mfma_16x16x32(kf[i], qf[j], acc[i][j]);
  }

  // ---- mask + exp + per-query denom (q = 16j + c; key = 16i + 4g + r) ----
  float invs[4];
  #pragma unroll
  for (int j = 0; j < 4; ++j) {
    const int q = 16 * j + c;
    const int padq = (int)((pm >> q) & 1);
    float sj = 0.f;
    #pragma unroll
    for (int i = 0; i < 4; ++i) {
      #pragma unroll
      for (int r = 0; r < 4; ++r) {
        const int key = 16 * i + 4 * g + r;
        const int padk = (int)((pm >> key) & 1);
        float sv = acc[i][j][r] * 0.125f + ((padk ^ padq) ? -1000.f : 0.f);
        float p = __expf(sv);
        if (i == 3) p = ((4 * g + r) == 0) ? p : 0.f;   // keys >= 49 forced 0
        acc[i][j][r] = p;
        sj += p;
      }
    }
    invs[j] = sj;
  }
  #pragma unroll
  for (int j = 0; j < 4; ++j) {
    float sj = invs[j];
    sj += __shfl_xor(sj, 16);
    sj += __shfl_xor(sj, 32);
    invs[j] = 1.0f / sj;
  }

  // ---- pack normalized P to f16, write LDS [q][key] (byte ^= (q&7)<<4) ----
  f16* pl = &plds[wv][0];
  const int swz = (c & 7) << 4;   // c&7 == q&7 for all j
  #pragma unroll
  for (int j = 0; j < 4; ++j) {
    const int q = 16 * j + c;
    const float inv = invs[j];
    #pragma unroll
    for (int i = 0; i < 4; ++i) {
      f16x4 pk;
      pk[0] = (f16)(acc[i][j][0] * inv);
      pk[1] = (f16)(acc[i][j][1] * inv);
      pk[2] = (f16)(acc[i][j][2] * inv);
      pk[3] = (f16)(acc[i][j][3] * inv);
      *(f16x4*)((char*)pl + q * 128 + ((32 * i + 8 * g) ^ swz)) = pk;
    }
  }

  // ---- O = P * V in two d-halves; V^T built in LDS from vreg ----
  f16* vl = &vlds[wv][0];
  f32x4 o[4][4];
  #pragma unroll
  for (int i = 0; i < 4; ++i)
    #pragma unroll
    for (int j = 0; j < 4; ++j) o[i][j] = (f32x4){0.f, 0.f, 0.f, 0.f};

  #pragma unroll
  for (int h = 0; h < 2; ++h) {
    #pragma unroll
    for (int q4 = 0; q4 < 4; ++q4) {
      const int d0 = 4 * h + q4;
      #pragma unroll
      for (int j = 0; j < 8; ++j) {
        const int dr = (8 * d0 + j) & 31;
        *(f16*)((char*)vl + dr * 128 + ((lane * 2) ^ (j << 4))) = vreg[d0][j];
      }
    }
    #pragma unroll
    for (int s = 0; s < 2; ++s) {
      f16x8 vf[2], pf[4];
      #pragma unroll
      for (int n = 0; n < 2; ++n)
        vf[n] = *(const f16x8*)((const char*)vl + (16 * n + c) * 128 + ((64 * s + 16 * g) ^ swz));
      #pragma unroll
      for (int jq = 0; jq < 4; ++jq)
        pf[jq] = *(const f16x8*)((const char*)pl + (16 * jq + c) * 128 + ((64 * s + 16 * g) ^ swz));
      #pragma unroll
      for (int jq = 0; jq < 4; ++jq)
        #pragma unroll
        for (int n = 0; n < 2; ++n)
          o[jq][2 * h + n] = mfma_16x16x32(pf[jq], vf[n], o[jq][2 * h + n]);
    }
  }

  // ---- store O rows q = 16jq + 4g + r (q<49), cols d = 16n + c ----
  f16* ob = og + ((size_t)bwi * 49) * 512 + head * 64;
  #pragma unroll
  for (int jq = 0; jq < 4; ++jq) {
    #pragma unroll
    for (int r = 0; r < 4; ++r) {
      const int q = 16 * jq + 4 * g + r;
      if (q < 49) {
        #pragma unroll
        for (int n = 0; n < 4; ++n)
          ob[(size_t)q * 512 + 16 * n + c] = (f16)o[jq][n][r];
      }
    }
  }
}

extern "C" void kernel_launch(void* const* d_in, const int* in_sizes, int n_in,
                              void* d_out, int out_size, void* d_ws, size_t ws_size,
                              hipStream_t stream)
{
  const float* x     = (const float*)d_in[0];
  const float* wqkv  = (const float*)d_in[1];
  const float* wproj = (const float*)d_in[2];
  const float* bproj = (const float*)d_in[3];
  float* out = (float*)d_out;

  // workspace layout (bytes); xh and ah share a region (xh dead before attn)
  char* ws = (char*)d_ws;
  f16* zp = (f16*)ws;                               // 1,024 B
  f16* xh = (f16*)(ws + 1024);                      // 104,603,648 B (region 116,006,912)
  f16* ah = xh;                                     // 116,006,912 B (after gemm1)
  f16* qh = (f16*)(ws + 1024 + 116006912LL);        // 116,006,912 B
  f16* kh = qh + 58003456LL;                        // 116,006,912 B
  f16* vh = kh + 58003456LL;                        // 151,519,232 B ([hw][64-stride][64])
  f16* wqkvT  = vh + 75759616LL;                    //   1,572,864 B
  f16* wprojT = wqkvT + 786432LL;                   //     524,288 B  (~501.6 MB total)

  cvt_x_kernel<<<2048, 256, 0, stream>>>(x, xh, zp);
  cvt_wT_kernel<<<(1536 * 512 + 255) / 256, 256, 0, stream>>>(wqkv, wqkvT, 512, 1536);
  cvt_wT_kernel<<<(512 * 512 + 255) / 256, 256, 0, stream>>>(wproj, wprojT, 512, 512);

  // 443 M-tiles of 256 x 6 N-tiles of 256
  gemm_kernel<0><<<443 * 6, 512, 0, stream>>>(xh, wqkvT, qh, kh, vh, nullptr, nullptr, zp);

  attn_kernel<<<NHW / 4, 256, 0, stream>>>(qh, kh, vh, ah);

  // 400 M-tiles of 256 x 2 N-tiles of 256
  gemm_kernel<1><<<400 * 2, 512, 0, stream>>>(ah, wprojT, nullptr, nullptr, nullptr, out, bproj, zp);
}

// Round 7
// 563.323 us; speedup vs baseline: 1.0752x; 1.0081x over previous
//
#include <hip/hip_runtime.h>
#include <hip/hip_fp16.h>
#include <stdint.h>

typedef _Float16 f16;
typedef __attribute__((ext_vector_type(4))) _Float16 f16x4;
typedef __attribute__((ext_vector_type(8))) _Float16 f16x8;
typedef __attribute__((ext_vector_type(4))) float f32x4;

#define DEVI static __device__ __forceinline__

// ---- constants for this problem ----
#define C_DIM 512
#define M1    113288   // 8*289*49 window-token rows
#define M2    102152   // 8*12769 pixel rows
#define NWIN  289
#define NTOK  49
#define NHW   18496    // 8*289*8 head-windows

DEVI void load_lds16(const f16* g, f16* l) {
  __builtin_amdgcn_global_load_lds((const __attribute__((address_space(1))) void*)g,
                                   (__attribute__((address_space(3))) void*)l,
                                   16, 0, 0);
}

DEVI f32x4 mfma_16x16x32(f16x8 a, f16x8 b, f32x4 c) {
  return __builtin_amdgcn_mfma_f32_16x16x32_f16(a, b, c, 0, 0, 0);
}

// ---------------- x -> f16 (and zero page init) ----------------
__global__ void cvt_x_kernel(const float* __restrict__ x, f16* __restrict__ xh,
                             f16* __restrict__ zp) {
  if (blockIdx.x == 0 && threadIdx.x < 64) {
    ((int4*)zp)[threadIdx.x] = make_int4(0, 0, 0, 0);  // 1024 B zeros
  }
  const int n8 = 6537728;  // 52,301,824 / 8
  int i = blockIdx.x * blockDim.x + threadIdx.x;
  for (; i < n8; i += gridDim.x * blockDim.x) {
    const float4* p = (const float4*)(x) + (size_t)i * 2;
    const float4 a = p[0], b = p[1];
    f16x8 o;
    o[0] = (f16)a.x; o[1] = (f16)a.y; o[2] = (f16)a.z; o[3] = (f16)a.w;
    o[4] = (f16)b.x; o[5] = (f16)b.y; o[6] = (f16)b.z; o[7] = (f16)b.w;
    *(f16x8*)(xh + (size_t)i * 8) = o;
  }
}

// ---------------- W [K][N] -> Wt f16 [N][K] ----------------
__global__ void cvt_wT_kernel(const float* __restrict__ w, f16* __restrict__ wt,
                              int K, int N) {
  const int i = blockIdx.x * blockDim.x + threadIdx.x;
  if (i < K * N) {
    const int n = i / K;
    const int k = i - n * K;
    wt[i] = (f16)w[(size_t)k * N + n];
  }
}

// ================= GEMM: C[M][N] = gather(A)[M][512] @ Bt[N][512]^T =============
// 128x128 block tile, 4 waves (64x64 per wave), BK=64, SINGLE 32 KB LDS buffer,
// 2 barriers per K-tile (32 MFMA per wave per barrier-pair -> 2x r3's ratio).
// LDS [128 rows][8 chunks of 16B], phys chunk = logical ^ (row&7) (conflict-free
// ds_read_b128, realized via inverse-swizzled GLOBAL source + linear gload dest).
// Overlap comes from 3-5 co-resident blocks per CU (m114 mechanism).
// MODE 0: A = xh (pixel rows, window-partition gather w/ zero pad);
//         q/k -> [hw][49][64] (stride 3136), v -> [hw][49][64] (stride 4096)
// MODE 1: A = ah (window-token rows, window-merge gather); out -> fp32 + bias
template<int MODE>
__global__ __launch_bounds__(256, 2)
void gemm_kernel(const f16* __restrict__ A, const f16* __restrict__ Bt,
                 f16* __restrict__ qo, f16* __restrict__ ko, f16* __restrict__ vo,
                 float* __restrict__ out, const float* __restrict__ bias,
                 const f16* __restrict__ zp)
{
  __shared__ __align__(16) f16 As[8192];  // [128][64] f16 = 16 KB
  __shared__ __align__(16) f16 Bs[8192];

  const int tid  = threadIdx.x;
  const int wave = tid >> 6;
  const int lane = tid & 63;
  const int l16  = lane & 15;
  const int g    = lane >> 4;

  constexpr int NTN = (MODE == 0) ? 12 : 4;
  // bijective XCD swizzle, tn-fastest (all N-passes of an A-tile on one XCD)
  const int nwg = gridDim.x;
  const int qq = nwg >> 3, rr = nwg & 7;
  const int xcd = blockIdx.x & 7, ib = blockIdx.x >> 3;
  const int wg = (xcd < rr ? xcd * (qq + 1) : rr * (qq + 1) + (xcd - rr) * qq) + ib;
  const int tn = wg % NTN;
  const int tm = wg / NTN;

  // ---- staging source pointers: 4 row-groups of 32, one 16B chunk per thread ----
  const int srow  = tid >> 3;   // 0..31
  const int chunk = tid & 7;    // phys chunk slot (linear LDS dest)
  const int lc    = chunk ^ (srow & 7);  // logical k-chunk fetched into this slot
  const f16* asrc[4];
  const f16* bsrc[4];
  #pragma unroll
  for (int c = 0; c < 4; ++c) {
    const int m = tm * 128 + c * 32 + srow;
    long src = 0; bool valid;
    if (MODE == 0) {
      const int b   = m / 14161;               // 289*49
      const int rem = m - b * 14161;
      const int wi  = rem / 49;
      const int t   = rem - wi * 49;
      const int wh = wi / 17, ww = wi - (wi / 17) * 17;
      const int th = t / 7,   tw = t - (t / 7) * 7;
      const int h = wh * 7 + th, w = ww * 7 + tw;
      valid = (m < M1) && (h < 113) && (w < 113);
      src = (long)b * 12769 + h * 113 + w;
    } else {
      const int b = m / 12769;
      const int p = m - b * 12769;
      const int h = p / 113, w = p - (p / 113) * 113;
      valid = (m < M2);
      src = (long)((b * NWIN + (h / 7) * 17 + (w / 7)) * NTOK + (h % 7) * 7 + (w % 7));
    }
    asrc[c] = valid ? (A + src * C_DIM + lc * 8) : zp;
    bsrc[c] = Bt + (long)(tn * 128 + c * 32 + srow) * C_DIM + lc * 8;
  }

  // ---- ds_read byte offsets (kh=0; kh=1 => ^64) ----
  int aoff[4], boff[4];
  #pragma unroll
  for (int i = 0; i < 4; ++i) {
    const int ra = (wave >> 1) * 64 + 16 * i + l16;
    aoff[i] = ra * 128 + ((g ^ (l16 & 7)) << 4);
    const int rb = (wave & 1) * 64 + 16 * i + l16;
    boff[i] = rb * 128 + ((g ^ (l16 & 7)) << 4);
  }

  f32x4 acc[4][4];
  #pragma unroll
  for (int i = 0; i < 4; ++i)
    #pragma unroll
    for (int j = 0; j < 4; ++j)
      acc[i][j] = (f32x4){0.f, 0.f, 0.f, 0.f};

  for (int kk = 0; kk < 8; ++kk) {       // K = 512 = 8 * 64
    __syncthreads();                     // prior tile's reads done (WAR)
    #pragma unroll
    for (int c = 0; c < 4; ++c) {
      load_lds16(asrc[c], &As[c * 2048 + wave * 512]);
      asrc[c] += 64;
    }
    #pragma unroll
    for (int c = 0; c < 4; ++c) {
      load_lds16(bsrc[c], &Bs[c * 2048 + wave * 512]);
      bsrc[c] += 64;
    }
    __syncthreads();                     // staging complete (vmcnt drained)

    #pragma unroll
    for (int kh = 0; kh < 2; ++kh) {
      f16x8 af[4], bf[4];
      #pragma unroll
      for (int i = 0; i < 4; ++i) af[i] = *(const f16x8*)((const char*)As + (aoff[i] ^ (kh << 6)));
      #pragma unroll
      for (int j = 0; j < 4; ++j) bf[j] = *(const f16x8*)((const char*)Bs + (boff[j] ^ (kh << 6)));
      #pragma unroll
      for (int i = 0; i < 4; ++i)
        #pragma unroll
        for (int j = 0; j < 4; ++j)
          acc[i][j] = mfma_16x16x32(af[i], bf[j], acc[i][j]);
    }
  }

  // ---- epilogue ----
  const int rowb = tm * 128 + (wave >> 1) * 64 + g * 4;
  const int colb = tn * 128 + (wave & 1) * 64 + l16;
  if (MODE == 0) {
    f16* outw = (tn < 4) ? qo : (tn < 8) ? ko : vo;
    const size_t stride = (tn < 8) ? 3136 : 4096;
    #pragma unroll
    for (int i = 0; i < 4; ++i) {
      #pragma unroll
      for (int j = 0; j < 4; ++j) {
        const int col  = colb + j * 16;
        const int head = (col >> 6) & 7;
        const int d    = col & 63;
        #pragma unroll
        for (int rg = 0; rg < 4; ++rg) {
          const int m = rowb + i * 16 + rg;
          if (m < M1) {
            const int bwi = m / 49;
            const int t   = m - bwi * 49;
            const size_t hw = (size_t)(bwi * 8 + head);
            outw[hw * stride + t * 64 + d] = (f16)acc[i][j][rg];
          }
        }
      }
    }
  } else {
    #pragma unroll
    for (int i = 0; i < 4; ++i) {
      #pragma unroll
      for (int j = 0; j < 4; ++j) {
        const int col = colb + j * 16;
        const float bb = bias[col];
        #pragma unroll
        for (int rg = 0; rg < 4; ++rg) {
          const int m = rowb + i * 16 + rg;
          if (m < M2) out[(size_t)m * C_DIM + col] = acc[i][j][rg] + bb;
        }
      }
    }
  }
}

// ---------------- MFMA attention: one wave per (b, window, head) ----------------
__global__ __launch_bounds__(256)
void attn_kernel(const f16* __restrict__ qg, const f16* __restrict__ kg,
                 const f16* __restrict__ vg, f16* __restrict__ og)
{
  __shared__ __align__(16) f16 plds[4][4096];  // per-wave [64q][64key], XOR-swizzled
  __shared__ __align__(16) f16 vlds[4][2048];  // per-wave [32d][64t] half, XOR-swizzled
  const int tid  = threadIdx.x;
  const int wv   = tid >> 6;
  const int lane = tid & 63;
  const int g    = lane >> 4;
  const int c    = lane & 15;
  const int hw   = blockIdx.x * 4 + wv;
  const int bwi  = hw >> 3;
  const int head = hw & 7;
  const int wi   = bwi % NWIN;
  const size_t bqk = (size_t)hw * 3136;
  const f16* vp = vg + (size_t)hw * 4096;

  // ---- V tile -> registers early (latency hides under QK^T); zero pad rows ----
  f16x8 vreg[8];
  #pragma unroll
  for (int d0 = 0; d0 < 8; ++d0)
    vreg[d0] = *(const f16x8*)(vp + lane * 64 + d0 * 8);
  if (lane >= 49) {
    #pragma unroll
    for (int d0 = 0; d0 < 8; ++d0) vreg[d0] = (f16x8){};
  }

  // pad-bit mask for tokens 0..48 of this window
  const int wh = wi / 17, ww = wi - (wi / 17) * 17;
  unsigned long long pm = 0;
  if (wh == 16) pm |= (((1ull << 49) - 1) & ~0x7Full);           // rows th>=1
  if (ww == 16) {
    unsigned long long cm = 0;
    #pragma unroll
    for (int r7 = 0; r7 < 7; ++r7) cm |= 0x7Eull << (7 * r7);    // cols tw>=1
    pm |= cm;
  }

  // ---- S^T = K * Q^T ----
  f32x4 acc[4][4];
  #pragma unroll
  for (int i = 0; i < 4; ++i)
    #pragma unroll
    for (int j = 0; j < 4; ++j) acc[i][j] = (f32x4){0.f, 0.f, 0.f, 0.f};

  const f16* kp = kg + bqk;
  const f16* qp = qg + bqk;
  #pragma unroll
  for (int s = 0; s < 2; ++s) {
    f16x8 kf[4], qf[4];
    #pragma unroll
    for (int i = 0; i < 4; ++i) kf[i] = *(const f16x8*)(kp + (16 * i + c) * 64 + 32 * s + 8 * g);
    #pragma unroll
    for (int j = 0; j < 4; ++j) qf[j] = *(const f16x8*)(qp + (16 * j + c) * 64 + 32 * s + 8 * g);
    #pragma unroll
    for (int i = 0; i < 4; ++i)
      #pragma unroll
      for (int j = 0; j < 4; ++j)
        acc[i][j] = mfma_16x16x32(kf[i], qf[j], acc[i][j]);
  }

  // ---- mask + exp + per-query denom (q = 16j + c; key = 16i + 4g + r) ----
  float invs[4];
  #pragma unroll
  for (int j = 0; j < 4; ++j) {
    const int q = 16 * j + c;
    const int padq = (int)((pm >> q) & 1);
    float sj = 0.f;
    #pragma unroll
    for (int i = 0; i < 4; ++i) {
      #pragma unroll
      for (int r = 0; r < 4; ++r) {
        const int key = 16 * i + 4 * g + r;
        const int padk = (int)((pm >> key) & 1);
        float sv = acc[i][j][r] * 0.125f + ((padk ^ padq) ? -1000.f : 0.f);
        float p = __expf(sv);
        if (i == 3) p = ((4 * g + r) == 0) ? p : 0.f;   // keys >= 49 forced 0
        acc[i][j][r] = p;
        sj += p;
      }
    }
    invs[j] = sj;
  }
  #pragma unroll
  for (int j = 0; j < 4; ++j) {
    float sj = invs[j];
    sj += __shfl_xor(sj, 16);
    sj += __shfl_xor(sj, 32);
    invs[j] = 1.0f / sj;
  }

  // ---- pack normalized P to f16, write LDS [q][key] (byte ^= (q&7)<<4) ----
  f16* pl = &plds[wv][0];
  const int swz = (c & 7) << 4;   // c&7 == q&7 for all j
  #pragma unroll
  for (int j = 0; j < 4; ++j) {
    const int q = 16 * j + c;
    const float inv = invs[j];
    #pragma unroll
    for (int i = 0; i < 4; ++i) {
      f16x4 pk;
      pk[0] = (f16)(acc[i][j][0] * inv);
      pk[1] = (f16)(acc[i][j][1] * inv);
      pk[2] = (f16)(acc[i][j][2] * inv);
      pk[3] = (f16)(acc[i][j][3] * inv);
      *(f16x4*)((char*)pl + q * 128 + ((32 * i + 8 * g) ^ swz)) = pk;
    }
  }

  // ---- O = P * V in two d-halves; V^T built in LDS from vreg ----
  f16* vl = &vlds[wv][0];
  f32x4 o[4][4];
  #pragma unroll
  for (int i = 0; i < 4; ++i)
    #pragma unroll
    for (int j = 0; j < 4; ++j) o[i][j] = (f32x4){0.f, 0.f, 0.f, 0.f};

  #pragma unroll
  for (int h = 0; h < 2; ++h) {
    #pragma unroll
    for (int q4 = 0; q4 < 4; ++q4) {
      const int d0 = 4 * h + q4;
      #pragma unroll
      for (int j = 0; j < 8; ++j) {
        const int dr = (8 * d0 + j) & 31;
        *(f16*)((char*)vl + dr * 128 + ((lane * 2) ^ (j << 4))) = vreg[d0][j];
      }
    }
    #pragma unroll
    for (int s = 0; s < 2; ++s) {
      f16x8 vf[2], pf[4];
      #pragma unroll
      for (int n = 0; n < 2; ++n)
        vf[n] = *(const f16x8*)((const char*)vl + (16 * n + c) * 128 + ((64 * s + 16 * g) ^ swz));
      #pragma unroll
      for (int jq = 0; jq < 4; ++jq)
        pf[jq] = *(const f16x8*)((const char*)pl + (16 * jq + c) * 128 + ((64 * s + 16 * g) ^ swz));
      #pragma unroll
      for (int jq = 0; jq < 4; ++jq)
        #pragma unroll
        for (int n = 0; n < 2; ++n)
          o[jq][2 * h + n] = mfma_16x16x32(pf[jq], vf[n], o[jq][2 * h + n]);
    }
  }

  // ---- store O rows q = 16jq + 4g + r (q<49), cols d = 16n + c ----
  f16* ob = og + ((size_t)bwi * 49) * 512 + head * 64;
  #pragma unroll
  for (int jq = 0; jq < 4; ++jq) {
    #pragma unroll
    for (int r = 0; r < 4; ++r) {
      const int q = 16 * jq + 4 * g + r;
      if (q < 49) {
        #pragma unroll
        for (int n = 0; n < 4; ++n)
          ob[(size_t)q * 512 + 16 * n + c] = (f16)o[jq][n][r];
      }
    }
  }
}

extern "C" void kernel_launch(void* const* d_in, const int* in_sizes, int n_in,
                              void* d_out, int out_size, void* d_ws, size_t ws_size,
                              hipStream_t stream)
{
  const float* x     = (const float*)d_in[0];
  const float* wqkv  = (const float*)d_in[1];
  const float* wproj = (const float*)d_in[2];
  const float* bproj = (const float*)d_in[3];
  float* out = (float*)d_out;

  // workspace layout (bytes); xh and ah share a region (xh dead before attn)
  char* ws = (char*)d_ws;
  f16* zp = (f16*)ws;                               // 1,024 B
  f16* xh = (f16*)(ws + 1024);                      // 104,603,648 B (region 116,006,912)
  f16* ah = xh;                                     // 116,006,912 B (after gemm1)
  f16* qh = (f16*)(ws + 1024 + 116006912LL);        // 116,006,912 B
  f16* kh = qh + 58003456LL;                        // 116,006,912 B
  f16* vh = kh + 58003456LL;                        // 151,519,232 B ([hw][64-stride][64])
  f16* wqkvT  = vh + 75759616LL;                    //   1,572,864 B
  f16* wprojT = wqkvT + 786432LL;                   //     524,288 B  (~501.6 MB total)

  cvt_x_kernel<<<2048, 256, 0, stream>>>(x, xh, zp);
  cvt_wT_kernel<<<(1536 * 512 + 255) / 256, 256, 0, stream>>>(wqkv, wqkvT, 512, 1536);
  cvt_wT_kernel<<<(512 * 512 + 255) / 256, 256, 0, stream>>>(wproj, wprojT, 512, 512);

  // 886 M-tiles of 128 x 12 N-tiles of 128
  gemm_kernel<0><<<886 * 12, 256, 0, stream>>>(xh, wqkvT, qh, kh, vh, nullptr, nullptr, zp);

  attn_kernel<<<NHW / 4, 256, 0, stream>>>(qh, kh, vh, ah);

  // 799 M-tiles of 128 x 4 N-tiles of 128
  gemm_kernel<1><<<799 * 4, 256, 0, stream>>>(ah, wprojT, nullptr, nullptr, nullptr, out, bproj, zp);
}

// Round 8
// 558.261 us; speedup vs baseline: 1.0850x; 1.0091x over previous
//
#include <hip/hip_runtime.h>
#include <hip/hip_fp16.h>
#include <stdint.h>

typedef _Float16 f16;
typedef __attribute__((ext_vector_type(4))) _Float16 f16x4;
typedef __attribute__((ext_vector_type(8))) _Float16 f16x8;
typedef __attribute__((ext_vector_type(4))) float f32x4;

#define DEVI static __device__ __forceinline__

// ---- constants for this problem ----
#define C_DIM 512
#define M1    113288   // 8*289*49 window-token rows
#define M2    102152   // 8*12769 pixel rows
#define NWIN  289
#define NTOK  49
#define NHW   18496    // 8*289*8 head-windows
#define QKV_STRIDE 3136  // 49*64 per head-window, q/k/v all

DEVI void load_lds16(const f16* g, f16* l) {
  __builtin_amdgcn_global_load_lds((const __attribute__((address_space(1))) void*)g,
                                   (__attribute__((address_space(3))) void*)l,
                                   16, 0, 0);
}

DEVI f32x4 mfma_16x16x32(f16x8 a, f16x8 b, f32x4 c) {
  return __builtin_amdgcn_mfma_f32_16x16x32_f16(a, b, c, 0, 0, 0);
}

// ---------------- x -> f16 (and zero page init) ----------------
__global__ void cvt_x_kernel(const float* __restrict__ x, f16* __restrict__ xh,
                             f16* __restrict__ zp) {
  if (blockIdx.x == 0 && threadIdx.x < 64) {
    ((int4*)zp)[threadIdx.x] = make_int4(0, 0, 0, 0);  // 1024 B zeros
  }
  const int n8 = 6537728;  // 52,301,824 / 8
  int i = blockIdx.x * blockDim.x + threadIdx.x;
  for (; i < n8; i += gridDim.x * blockDim.x) {
    const float4* p = (const float4*)(x) + (size_t)i * 2;
    const float4 a = p[0], b = p[1];
    f16x8 o;
    o[0] = (f16)a.x; o[1] = (f16)a.y; o[2] = (f16)a.z; o[3] = (f16)a.w;
    o[4] = (f16)b.x; o[5] = (f16)b.y; o[6] = (f16)b.z; o[7] = (f16)b.w;
    *(f16x8*)(xh + (size_t)i * 8) = o;
  }
}

// ---------------- W [K][N] -> Wt f16 [N][K] ----------------
__global__ void cvt_wT_kernel(const float* __restrict__ w, f16* __restrict__ wt,
                              int K, int N) {
  const int i = blockIdx.x * blockDim.x + threadIdx.x;
  if (i < K * N) {
    const int n = i / K;
    const int k = i - n * K;
    wt[i] = (f16)w[(size_t)k * N + n];
  }
}

// ================= GEMM: C[M][N] = gather(A)[M][512] @ Bt[N][512]^T =============
// 128x128 block tile, 4 waves (64x64 per wave), BK=64, SINGLE 32 KB LDS buffer,
// 2 barriers per K-tile. LDS [128 rows][8 chunks of 16B], phys chunk =
// logical ^ (row&7) via inverse-swizzled GLOBAL source + linear gload dest.
// MODE 0 epilogue: LDS-transpose (reuse As/Bs space) -> coalesced f16x8 stores.
// MODE 0: q/k/v all -> [hw][49][64] f16 (stride 3136)
// MODE 1: A = ah (window-merge gather); out -> fp32 + bias (old scatter epilogue)
template<int MODE>
__global__ __launch_bounds__(256, 2)
void gemm_kernel(const f16* __restrict__ A, const f16* __restrict__ Bt,
                 f16* __restrict__ qo, f16* __restrict__ ko, f16* __restrict__ vo,
                 float* __restrict__ out, const float* __restrict__ bias,
                 const f16* __restrict__ zp)
{
  __shared__ __align__(16) f16 S[16384];  // 32 KB: As | Bs during K-loop; Cs in epilogue
  f16* As = S;
  f16* Bs = S + 8192;

  const int tid  = threadIdx.x;
  const int wave = tid >> 6;
  const int lane = tid & 63;
  const int l16  = lane & 15;
  const int g    = lane >> 4;

  constexpr int NTN = (MODE == 0) ? 12 : 4;
  // bijective XCD swizzle, tn-fastest (all N-passes of an A-tile on one XCD)
  const int nwg = gridDim.x;
  const int qq = nwg >> 3, rr = nwg & 7;
  const int xcd = blockIdx.x & 7, ib = blockIdx.x >> 3;
  const int wg = (xcd < rr ? xcd * (qq + 1) : rr * (qq + 1) + (xcd - rr) * qq) + ib;
  const int tn = wg % NTN;
  const int tm = wg / NTN;

  // ---- staging source pointers: 4 row-groups of 32, one 16B chunk per thread ----
  const int srow  = tid >> 3;   // 0..31
  const int chunk = tid & 7;    // phys chunk slot (linear LDS dest)
  const int lc    = chunk ^ (srow & 7);  // logical k-chunk fetched into this slot
  const f16* asrc[4];
  const f16* bsrc[4];
  #pragma unroll
  for (int c = 0; c < 4; ++c) {
    const int m = tm * 128 + c * 32 + srow;
    long src = 0; bool valid;
    if (MODE == 0) {
      const int b   = m / 14161;               // 289*49
      const int rem = m - b * 14161;
      const int wi  = rem / 49;
      const int t   = rem - wi * 49;
      const int wh = wi / 17, ww = wi - (wi / 17) * 17;
      const int th = t / 7,   tw = t - (t / 7) * 7;
      const int h = wh * 7 + th, w = ww * 7 + tw;
      valid = (m < M1) && (h < 113) && (w < 113);
      src = (long)b * 12769 + h * 113 + w;
    } else {
      const int b = m / 12769;
      const int p = m - b * 12769;
      const int h = p / 113, w = p - (p / 113) * 113;
      valid = (m < M2);
      src = (long)((b * NWIN + (h / 7) * 17 + (w / 7)) * NTOK + (h % 7) * 7 + (w % 7));
    }
    asrc[c] = valid ? (A + src * C_DIM + lc * 8) : zp;
    bsrc[c] = Bt + (long)(tn * 128 + c * 32 + srow) * C_DIM + lc * 8;
  }

  // ---- ds_read byte offsets (kh=0; kh=1 => ^64) ----
  int aoff[4], boff[4];
  #pragma unroll
  for (int i = 0; i < 4; ++i) {
    const int ra = (wave >> 1) * 64 + 16 * i + l16;
    aoff[i] = ra * 128 + ((g ^ (l16 & 7)) << 4);
    const int rb = (wave & 1) * 64 + 16 * i + l16;
    boff[i] = rb * 128 + ((g ^ (l16 & 7)) << 4);
  }

  f32x4 acc[4][4];
  #pragma unroll
  for (int i = 0; i < 4; ++i)
    #pragma unroll
    for (int j = 0; j < 4; ++j)
      acc[i][j] = (f32x4){0.f, 0.f, 0.f, 0.f};

  for (int kk = 0; kk < 8; ++kk) {       // K = 512 = 8 * 64
    __syncthreads();                     // prior tile's reads done (WAR)
    #pragma unroll
    for (int c = 0; c < 4; ++c) {
      load_lds16(asrc[c], &As[c * 2048 + wave * 512]);
      asrc[c] += 64;
    }
    #pragma unroll
    for (int c = 0; c < 4; ++c) {
      load_lds16(bsrc[c], &Bs[c * 2048 + wave * 512]);
      bsrc[c] += 64;
    }
    __syncthreads();                     // staging complete (vmcnt drained)

    #pragma unroll
    for (int kh = 0; kh < 2; ++kh) {
      f16x8 af[4], bf[4];
      #pragma unroll
      for (int i = 0; i < 4; ++i) af[i] = *(const f16x8*)((const char*)As + (aoff[i] ^ (kh << 6)));
      #pragma unroll
      for (int j = 0; j < 4; ++j) bf[j] = *(const f16x8*)((const char*)Bs + (boff[j] ^ (kh << 6)));
      #pragma unroll
      for (int i = 0; i < 4; ++i)
        #pragma unroll
        for (int j = 0; j < 4; ++j)
          acc[i][j] = mfma_16x16x32(af[i], bf[j], acc[i][j]);
    }
  }

  // ---- epilogue ----
  if (MODE == 0) {
    // LDS-transpose: Cs[128 rows][128 cols] f16, byte-swizzle ^((row>>2&3)<<5)
    __syncthreads();                       // all waves done reading As/Bs
    char* Cs = (char*)S;
    const int rw0 = (wave >> 1) * 64 + g * 4;
    const int cl0 = (wave & 1) * 64 + l16;
    #pragma unroll
    for (int i = 0; i < 4; ++i) {
      #pragma unroll
      for (int rg = 0; rg < 4; ++rg) {
        const int row = rw0 + i * 16 + rg;
        const int xr  = ((row >> 2) & 3) << 5;
        #pragma unroll
        for (int j = 0; j < 4; ++j) {
          const int col = cl0 + j * 16;
          *(f16*)(Cs + row * 256 + ((col * 2) ^ xr)) = (f16)acc[i][j][rg];
        }
      }
    }
    __syncthreads();
    // read-out: thread -> (row, 64-col half); coalesced 16B global stores
    const int row  = tid >> 1;
    const int half = tid & 1;
    const int m = tm * 128 + row;
    if (m < M1) {
      const int bwi = m / 49;
      const int t   = m - bwi * 49;
      const int cwi = tn * 2 + half;            // 64-col strip index 0..23
      f16* outw = (cwi < 8) ? qo : (cwi < 16) ? ko : vo;
      const int head = cwi & 7;
      f16* dst = outw + (size_t)(bwi * 8 + head) * QKV_STRIDE + t * 64;
      const int xr = ((row >> 2) & 3) << 5;
      #pragma unroll
      for (int c = 0; c < 8; ++c) {
        f16x8 v = *(const f16x8*)(Cs + row * 256 + ((half * 128 + c * 16) ^ xr));
        *(f16x8*)(dst + c * 8) = v;
      }
    }
  } else {
    const int rowb = tm * 128 + (wave >> 1) * 64 + g * 4;
    const int colb = tn * 128 + (wave & 1) * 64 + l16;
    #pragma unroll
    for (int i = 0; i < 4; ++i) {
      #pragma unroll
      for (int j = 0; j < 4; ++j) {
        const int col = colb + j * 16;
        const float bb = bias[col];
        #pragma unroll
        for (int rg = 0; rg < 4; ++rg) {
          const int m = rowb + i * 16 + rg;
          if (m < M2) out[(size_t)m * C_DIM + col] = acc[i][j][rg] + bb;
        }
      }
    }
  }
}

// ---------------- MFMA attention: one wave per (b, window, head) ----------------
__global__ __launch_bounds__(256)
void attn_kernel(const f16* __restrict__ qg, const f16* __restrict__ kg,
                 const f16* __restrict__ vg, f16* __restrict__ og)
{
  __shared__ __align__(16) f16 plds[4][4096];  // per-wave [64q][64key], XOR-swizzled
  __shared__ __align__(16) f16 vlds[4][2048];  // per-wave [32d][64t] half, XOR-swizzled
  const int tid  = threadIdx.x;
  const int wv   = tid >> 6;
  const int lane = tid & 63;
  const int g    = lane >> 4;
  const int c    = lane & 15;
  const int hw   = blockIdx.x * 4 + wv;
  const int bwi  = hw >> 3;
  const int head = hw & 7;
  const int wi   = bwi % NWIN;
  const size_t bqk = (size_t)hw * QKV_STRIDE;
  const f16* vp = vg + (size_t)hw * QKV_STRIDE;

  // ---- V tile -> registers early (latency hides under QK^T); zero pad rows ----
  f16x8 vreg[8];
  #pragma unroll
  for (int d0 = 0; d0 < 8; ++d0)
    vreg[d0] = *(const f16x8*)(vp + lane * 64 + d0 * 8);
  if (lane >= 49) {
    #pragma unroll
    for (int d0 = 0; d0 < 8; ++d0) vreg[d0] = (f16x8){};
  }

  // pad-bit mask for tokens 0..48 of this window
  const int wh = wi / 17, ww = wi - (wi / 17) * 17;
  unsigned long long pm = 0;
  if (wh == 16) pm |= (((1ull << 49) - 1) & ~0x7Full);           // rows th>=1
  if (ww == 16) {
    unsigned long long cm = 0;
    #pragma unroll
    for (int r7 = 0; r7 < 7; ++r7) cm |= 0x7Eull << (7 * r7);    // cols tw>=1
    pm |= cm;
  }

  // ---- S^T = K * Q^T ----
  f32x4 acc[4][4];
  #pragma unroll
  for (int i = 0; i < 4; ++i)
    #pragma unroll
    for (int j = 0; j < 4; ++j) acc[i][j] = (f32x4){0.f, 0.f, 0.f, 0.f};

  const f16* kp = kg + bqk;
  const f16* qp = qg + bqk;
  #pragma unroll
  for (int s = 0; s < 2; ++s) {
    f16x8 kf[4], qf[4];
    #pragma unroll
    for (int i = 0; i < 4; ++i) kf[i] = *(const f16x8*)(kp + (16 * i + c) * 64 + 32 * s + 8 * g);
    #pragma unroll
    for (int j = 0; j < 4; ++j) qf[j] = *(const f16x8*)(qp + (16 * j + c) * 64 + 32 * s + 8 * g);
    #pragma unroll
    for (int i = 0; i < 4; ++i)
      #pragma unroll
      for (int j = 0; j < 4; ++j)
        acc[i][j] = mfma_16x16x32(kf[i], qf[j], acc[i][j]);
  }

  // ---- mask + exp + per-query denom (q = 16j + c; key = 16i + 4g + r) ----
  float invs[4];
  #pragma unroll
  for (int j = 0; j < 4; ++j) {
    const int q = 16 * j + c;
    const int padq = (int)((pm >> q) & 1);
    float sj = 0.f;
    #pragma unroll
    for (int i = 0; i < 4; ++i) {
      #pragma unroll
      for (int r = 0; r < 4; ++r) {
        const int key = 16 * i + 4 * g + r;
        const int padk = (int)((pm >> key) & 1);
        float sv = acc[i][j][r] * 0.125f + ((padk ^ padq) ? -1000.f : 0.f);
        float p = __expf(sv);
        if (i == 3) p = ((4 * g + r) == 0) ? p : 0.f;   // keys >= 49 forced 0
        acc[i][j][r] = p;
        sj += p;
      }
    }
    invs[j] = sj;
  }
  #pragma unroll
  for (int j = 0; j < 4; ++j) {
    float sj = invs[j];
    sj += __shfl_xor(sj, 16);
    sj += __shfl_xor(sj, 32);
    invs[j] = 1.0f / sj;
  }

  // ---- pack normalized P to f16, write LDS [q][key] (byte ^= (q&7)<<4) ----
  f16* pl = &plds[wv][0];
  const int swz = (c & 7) << 4;   // c&7 == q&7 for all j
  #pragma unroll
  for (int j = 0; j < 4; ++j) {
    const int q = 16 * j + c;
    const float inv = invs[j];
    #pragma unroll
    for (int i = 0; i < 4; ++i) {
      f16x4 pk;
      pk[0] = (f16)(acc[i][j][0] * inv);
      pk[1] = (f16)(acc[i][j][1] * inv);
      pk[2] = (f16)(acc[i][j][2] * inv);
      pk[3] = (f16)(acc[i][j][3] * inv);
      *(f16x4*)((char*)pl + q * 128 + ((32 * i + 8 * g) ^ swz)) = pk;
    }
  }

  // ---- O = P * V in two d-halves; V^T built in LDS from vreg ----
  f16* vl = &vlds[wv][0];
  f32x4 o[4][4];
  #pragma unroll
  for (int i = 0; i < 4; ++i)
    #pragma unroll
    for (int j = 0; j < 4; ++j) o[i][j] = (f32x4){0.f, 0.f, 0.f, 0.f};

  #pragma unroll
  for (int h = 0; h < 2; ++h) {
    #pragma unroll
    for (int q4 = 0; q4 < 4; ++q4) {
      const int d0 = 4 * h + q4;
      #pragma unroll
      for (int j = 0; j < 8; ++j) {
        const int dr = (8 * d0 + j) & 31;
        *(f16*)((char*)vl + dr * 128 + ((lane * 2) ^ (j << 4))) = vreg[d0][j];
      }
    }
    #pragma unroll
    for (int s = 0; s < 2; ++s) {
      f16x8 vf[2], pf[4];
      #pragma unroll
      for (int n = 0; n < 2; ++n)
        vf[n] = *(const f16x8*)((const char*)vl + (16 * n + c) * 128 + ((64 * s + 16 * g) ^ swz));
      #pragma unroll
      for (int jq = 0; jq < 4; ++jq)
        pf[jq] = *(const f16x8*)((const char*)pl + (16 * jq + c) * 128 + ((64 * s + 16 * g) ^ swz));
      #pragma unroll
      for (int jq = 0; jq < 4; ++jq)
        #pragma unroll
        for (int n = 0; n < 2; ++n)
          o[jq][2 * h + n] = mfma_16x16x32(pf[jq], vf[n], o[jq][2 * h + n]);
    }
  }

  // ---- store O rows q = 16jq + 4g + r (q<49), cols d = 16n + c ----
  f16* ob = og + ((size_t)bwi * 49) * 512 + head * 64;
  #pragma unroll
  for (int jq = 0; jq < 4; ++jq) {
    #pragma unroll
    for (int r = 0; r < 4; ++r) {
      const int q = 16 * jq + 4 * g + r;
      if (q < 49) {
        #pragma unroll
        for (int n = 0; n < 4; ++n)
          ob[(size_t)q * 512 + 16 * n + c] = (f16)o[jq][n][r];
      }
    }
  }
}

extern "C" void kernel_launch(void* const* d_in, const int* in_sizes, int n_in,
                              void* d_out, int out_size, void* d_ws, size_t ws_size,
                              hipStream_t stream)
{
  const float* x     = (const float*)d_in[0];
  const float* wqkv  = (const float*)d_in[1];
  const float* wproj = (const float*)d_in[2];
  const float* bproj = (const float*)d_in[3];
  float* out = (float*)d_out;

  // workspace layout (bytes); xh and ah share a region (xh dead before attn)
  char* ws = (char*)d_ws;
  f16* zp = (f16*)ws;                               // 1,024 B
  f16* xh = (f16*)(ws + 1024);                      // 104,603,648 B (region 116,006,912)
  f16* ah = xh;                                     // 116,006,912 B (after gemm1)
  f16* qh = (f16*)(ws + 1024 + 116006912LL);        // 116,006,912 B
  f16* kh = qh + 58003456LL;                        // 116,006,912 B
  f16* vh = kh + 58003456LL;                        // 116,011,008 B (+4 KB overrun pad)
  f16* wqkvT  = vh + 58005504LL;                    //   1,572,864 B
  f16* wprojT = wqkvT + 786432LL;                   //     524,288 B  (~466 MB total)

  cvt_x_kernel<<<2048, 256, 0, stream>>>(x, xh, zp);
  cvt_wT_kernel<<<(1536 * 512 + 255) / 256, 256, 0, stream>>>(wqkv, wqkvT, 512, 1536);
  cvt_wT_kernel<<<(512 * 512 + 255) / 256, 256, 0, stream>>>(wproj, wprojT, 512, 512);

  // 886 M-tiles of 128 x 12 N-tiles of 128
  gemm_kernel<0><<<886 * 12, 256, 0, stream>>>(xh, wqkvT, qh, kh, vh, nullptr, nullptr, zp);

  attn_kernel<<<NHW / 4, 256, 0, stream>>>(qh, kh, vh, ah);

  // 799 M-tiles of 128 x 4 N-tiles of 128
  gemm_kernel<1><<<799 * 4, 256, 0, stream>>>(ah, wprojT, nullptr, nullptr, nullptr, out, bproj, zp);
}